// Round 1
// baseline (229.651 us; speedup 1.0000x reference)
//
#include <hip/hip_runtime.h>

// ---------------- problem constants (fixed shapes from setup_inputs) --------
constexpr int B_  = 16;
constexpr int L1_ = 65536;
constexpr int L2_ = 131072;
constexpr int S_  = L1_ + L2_;
constexpr int SD_ = 3;
constexpr int KS_ = 8;
constexpr int C_  = 16;
constexpr int E_  = 256;
constexpr int K2_ = L2_ / KS_;   // 16384 y-rows per batch
constexpr int T_  = L1_ / KS_;   // 8192 out-rows per batch

// ---------------- ws layout (element offsets, 4-byte units) -----------------
// [0, 32768)                  : wT  float  (32 kq * 256 e * 4)  = 128 KB
// [32768, 32768+B*L1)         : rank int   (4 MB)
// next 1024                   : cnt  int
// then                        : y    float B*K2*C (16 MB)
constexpr size_t WT_OFF   = 0;
constexpr size_t RANK_OFF = 32768;
constexpr size_t CNT_OFF  = RANK_OFF + (size_t)B_ * L1_;
constexpr size_t Y_OFF    = CNT_OFF + 1024;          // 16B-aligned (checked)

// ---------------- prep: transpose w_lat[e][c][s] -> wT4[kq][e][j] -----------
// contraction index k = s*16 + c  (matches xs layout below); kq = k/4, j = k%4
__global__ void prep_wT(const float* __restrict__ w_lat, float* __restrict__ wT) {
    int kq = blockIdx.x;          // 0..31
    int e  = threadIdx.x;         // 0..255
    float t[4];
#pragma unroll
    for (int j = 0; j < 4; ++j) {
        int k = kq * 4 + j;
        int s = k >> 4, c = k & 15;
        t[j] = w_lat[e * (C_ * KS_) + c * KS_ + s];
    }
    ((float4*)wT)[kq * E_ + e] = make_float4(t[0], t[1], t[2], t[3]);
}

// ---------------- pass 1: per-segment mask counts (SEG = 1024 tokens) -------
__global__ void count_kernel(const int* __restrict__ value, int* __restrict__ cnt) {
    int b = blockIdx.x >> 6, seg = blockIdx.x & 63, tid = threadIdx.x;
    const int4 v = *(const int4*)(value + (size_t)b * S_ + seg * 1024 + tid * 4);
    int c = (v.x == 2) + (v.y == 2) + (v.z == 2) + (v.w == 2);
    __shared__ int sd[256];
    sd[tid] = c;
    __syncthreads();
    for (int o = 128; o > 0; o >>= 1) {
        if (tid < o) sd[tid] += sd[tid + o];
        __syncthreads();
    }
    if (tid == 0) cnt[blockIdx.x] = sd[0];
}

// ---------------- pass 2: exclusive scan of 64 segment counts per batch -----
__global__ void scan_kernel(int* __restrict__ cnt) {
    int tid = threadIdx.x;                 // 1024 threads: (b = tid>>6, seg = tid&63)
    int c = cnt[tid];
    __shared__ int sd[1024];
    sd[tid] = c;
    __syncthreads();
    for (int o = 1; o < 64; o <<= 1) {
        int t = ((tid & 63) >= o) ? sd[tid - o] : 0;
        __syncthreads();
        sd[tid] += t;
        __syncthreads();
    }
    cnt[tid] = sd[tid] - c;                // exclusive
}

// ---------------- pass 3: per-token rank = cumsum(mask)-1 -------------------
__global__ void rank_kernel(const int* __restrict__ value, const int* __restrict__ cnt,
                            int* __restrict__ rank) {
    int b = blockIdx.x >> 6, seg = blockIdx.x & 63, tid = threadIdx.x;
    size_t base = (size_t)b * S_ + seg * 1024 + tid * 4;
    const int4 v = *(const int4*)(value + base);
    int m0 = (v.x == 2), m1 = (v.y == 2), m2 = (v.z == 2), m3 = (v.w == 2);
    int c = m0 + m1 + m2 + m3;
    __shared__ int sd[256];
    sd[tid] = c;
    __syncthreads();
    for (int o = 1; o < 256; o <<= 1) {
        int t = (tid >= o) ? sd[tid - o] : 0;
        __syncthreads();
        sd[tid] += t;
        __syncthreads();
    }
    int run = cnt[blockIdx.x] + sd[tid] - c;   // exclusive prefix for this thread
    int4 r;
    run += m0; r.x = run - 1;
    run += m1; r.y = run - 1;
    run += m2; r.z = run - 1;
    run += m3; r.w = run - 1;
    *(int4*)(rank + (size_t)b * L1_ + seg * 1024 + tid * 4) = r;
}

// ---------------- y conv: one thread per (b,k) -------------------------------
__global__ void y_kernel(const int* __restrict__ value, const int* __restrict__ depth,
                         const int* __restrict__ pos,
                         const float* __restrict__ w_v2, const float* __restrict__ b_v2,
                         const float* __restrict__ w_d2, const float* __restrict__ b_d2,
                         const float* __restrict__ w_p2, const float* __restrict__ b_p2,
                         float* __restrict__ y) {
    int idx = blockIdx.x * 256 + threadIdx.x;       // = b*K2_ + k
    size_t g = (size_t)(idx >> 14) * S_ + L1_ + (size_t)(idx & (K2_ - 1)) * KS_;
    int4 va = *(const int4*)(value + g), vb = *(const int4*)(value + g + 4);
    int4 da = *(const int4*)(depth + g), db = *(const int4*)(depth + g + 4);
    float vv[8] = {(float)va.x, (float)va.y, (float)va.z, (float)va.w,
                   (float)vb.x, (float)vb.y, (float)vb.z, (float)vb.w};
    float dd[8] = {(float)da.x, (float)da.y, (float)da.z, (float)da.w,
                   (float)db.x, (float)db.y, (float)db.z, (float)db.w};
    size_t p = g * SD_;
    int pi[24];
#pragma unroll
    for (int q = 0; q < 6; ++q) {
        int4 t = *(const int4*)(pos + p + q * 4);
        pi[q * 4 + 0] = t.x; pi[q * 4 + 1] = t.y; pi[q * 4 + 2] = t.z; pi[q * 4 + 3] = t.w;
    }
    float pp[24];
#pragma unroll
    for (int q = 0; q < 24; ++q) pp[q] = (float)pi[q];

    float o[16];
#pragma unroll
    for (int c = 0; c < C_; ++c) {
        float acc = b_v2[c] + b_d2[c] + b_p2[c] + b_p2[C_ + c] + b_p2[2 * C_ + c];
#pragma unroll
        for (int s = 0; s < KS_; ++s) {
            acc = fmaf(vv[s], w_v2[c * KS_ + s], acc);
            acc = fmaf(dd[s], w_d2[c * KS_ + s], acc);
            acc = fmaf(pp[s * 3 + 0], w_p2[(0 * C_ + c) * KS_ + s], acc);
            acc = fmaf(pp[s * 3 + 1], w_p2[(1 * C_ + c) * KS_ + s], acc);
            acc = fmaf(pp[s * 3 + 2], w_p2[(2 * C_ + c) * KS_ + s], acc);
        }
        o[c] = acc;
    }
    float4* yo = (float4*)(y + (size_t)idx * C_);
    yo[0] = make_float4(o[0],  o[1],  o[2],  o[3]);
    yo[1] = make_float4(o[4],  o[5],  o[6],  o[7]);
    yo[2] = make_float4(o[8],  o[9],  o[10], o[11]);
    yo[3] = make_float4(o[12], o[13], o[14], o[15]);
}

// ---------------- fused x-build + latent GEMM --------------------------------
// block = 256 threads; covers 16 output rows (=128 layer-1 tokens) x 256 e.
// Phase A: build xs[16 rows][128 k] in LDS (k = s*16+c -> flat token*16+c).
// Phase B: thread e accumulates 16 rows over k with float4 wT loads.
__global__ __launch_bounds__(256) void out_kernel(
    const int* __restrict__ value, const int* __restrict__ depth,
    const int* __restrict__ pos,
    const float* __restrict__ w_v1, const float* __restrict__ b_v1,
    const float* __restrict__ w_d1, const float* __restrict__ b_d1,
    const float* __restrict__ w_p1, const float* __restrict__ b_p1,
    const float* __restrict__ b_lat,
    const float* __restrict__ wT, const int* __restrict__ rank,
    const float* __restrict__ y, float* __restrict__ out) {
    __shared__ float xs[2048];
    __shared__ float wA[96];   // [0:16) wv1 [16:32) wd1 [32:48) cb1 [48:96) wp1[a*16+c]
    int tid = threadIdx.x;
    int b = blockIdx.x >> 9, tile = blockIdx.x & 511;

    if (tid < 16) {
        wA[tid]      = w_v1[tid];
        wA[16 + tid] = w_d1[tid];
        wA[32 + tid] = b_v1[tid] + b_d1[tid] + b_p1[tid] + b_p1[16 + tid] + b_p1[32 + tid];
    }
    if (tid < 48) wA[48 + tid] = w_p1[tid];
    __syncthreads();

    // -------- Phase A: two threads per token (hf = low/high 8 channels)
    int tt = tid >> 1, hf = tid & 1;
    size_t l  = (size_t)tile * 128 + tt;
    size_t gl = (size_t)b * S_ + l;
    int v = value[gl];
    float x8[8];
    if (v == 2) {
        int k = rank[(size_t)b * L1_ + l];
        const float4* yp = (const float4*)(y + ((size_t)b * K2_ + (size_t)k) * C_ + hf * 8);
        float4 a = yp[0], c4 = yp[1];
        x8[0] = a.x;  x8[1] = a.y;  x8[2] = a.z;  x8[3] = a.w;
        x8[4] = c4.x; x8[5] = c4.y; x8[6] = c4.z; x8[7] = c4.w;
    } else {
        float fv = (float)v, fd = (float)depth[gl];
        float p0 = (float)pos[gl * 3 + 0];
        float p1 = (float)pos[gl * 3 + 1];
        float p2 = (float)pos[gl * 3 + 2];
#pragma unroll
        for (int j = 0; j < 8; ++j) {
            int c = hf * 8 + j;
            float acc = wA[32 + c];
            acc = fmaf(fv, wA[c],      acc);
            acc = fmaf(fd, wA[16 + c], acc);
            acc = fmaf(p0, wA[48 + c], acc);
            acc = fmaf(p1, wA[64 + c], acc);
            acc = fmaf(p2, wA[80 + c], acc);
            x8[j] = acc;
        }
    }
    float4* xp = (float4*)&xs[tt * 16 + hf * 8];
    xp[0] = make_float4(x8[0], x8[1], x8[2], x8[3]);
    xp[1] = make_float4(x8[4], x8[5], x8[6], x8[7]);
    __syncthreads();

    // -------- Phase B: thread = one e column, 16 row accumulators
    int e = tid;
    float bl = b_lat[e];
    float acc[16];
#pragma unroll
    for (int r = 0; r < 16; ++r) acc[r] = bl;

    const float4* wp = (const float4*)wT;
#pragma unroll 4
    for (int kq = 0; kq < 32; ++kq) {
        float4 w4 = wp[kq * E_ + e];
#pragma unroll
        for (int r = 0; r < 16; ++r) {
            float4 x4 = *(const float4*)&xs[r * 128 + kq * 4];
            acc[r] = fmaf(x4.x, w4.x, acc[r]);
            acc[r] = fmaf(x4.y, w4.y, acc[r]);
            acc[r] = fmaf(x4.z, w4.z, acc[r]);
            acc[r] = fmaf(x4.w, w4.w, acc[r]);
        }
    }
    size_t ob = ((size_t)b * T_ + (size_t)tile * 16) * E_ + e;
#pragma unroll
    for (int r = 0; r < 16; ++r) out[ob + (size_t)r * E_] = acc[r];
}

// ---------------- launch ------------------------------------------------------
extern "C" void kernel_launch(void* const* d_in, const int* in_sizes, int n_in,
                              void* d_out, int out_size, void* d_ws, size_t ws_size,
                              hipStream_t stream) {
    const int*   value = (const int*)d_in[0];
    const int*   depth = (const int*)d_in[1];
    const int*   pos   = (const int*)d_in[2];
    // d_in[3] = len1 (static 65536, baked into constants)
    const float* w_v1 = (const float*)d_in[4];
    const float* b_v1 = (const float*)d_in[5];
    const float* w_d1 = (const float*)d_in[6];
    const float* b_d1 = (const float*)d_in[7];
    const float* w_p1 = (const float*)d_in[8];
    const float* b_p1 = (const float*)d_in[9];
    const float* w_v2 = (const float*)d_in[10];
    const float* b_v2 = (const float*)d_in[11];
    const float* w_d2 = (const float*)d_in[12];
    const float* b_d2 = (const float*)d_in[13];
    const float* w_p2 = (const float*)d_in[14];
    const float* b_p2 = (const float*)d_in[15];
    const float* w_lat = (const float*)d_in[16];
    const float* b_lat = (const float*)d_in[17];

    float* outp = (float*)d_out;
    float* wsf  = (float*)d_ws;
    int*   wsi  = (int*)d_ws;

    float* wT   = wsf + WT_OFF;
    int*   rank = wsi + RANK_OFF;
    int*   cnt  = wsi + CNT_OFF;
    float* y    = wsf + Y_OFF;

    prep_wT<<<32, 256, 0, stream>>>(w_lat, wT);
    count_kernel<<<B_ * 64, 256, 0, stream>>>(value, cnt);
    scan_kernel<<<1, 1024, 0, stream>>>(cnt);
    rank_kernel<<<B_ * 64, 256, 0, stream>>>(value, cnt, rank);
    y_kernel<<<(B_ * K2_) / 256, 256, 0, stream>>>(value, depth, pos,
                                                   w_v2, b_v2, w_d2, b_d2, w_p2, b_p2, y);
    out_kernel<<<B_ * 512, 256, 0, stream>>>(value, depth, pos,
                                             w_v1, b_v1, w_d1, b_d1, w_p1, b_p1,
                                             b_lat, wT, rank, y, outp);
}

// Round 2
// 85.445 us; speedup vs baseline: 2.6877x; 2.6877x over previous
//
#include <hip/hip_runtime.h>

// ---------------- problem constants (fixed shapes from setup_inputs) --------
constexpr int B_  = 16;
constexpr int L1_ = 65536;
constexpr int L2_ = 131072;
constexpr int S_  = L1_ + L2_;
constexpr int SD_ = 3;
constexpr int KS_ = 8;
constexpr int C_  = 16;
constexpr int E_  = 256;
constexpr int K2_ = L2_ / KS_;   // 16384 y-rows per batch
constexpr int T_  = L1_ / KS_;   // 8192 out-rows per batch

typedef __attribute__((ext_vector_type(8))) short bf16x8;
typedef __attribute__((ext_vector_type(4))) float f32x4;

// ---------------- ws layout (element offsets, 4-byte units) -----------------
// [0, 16384)            : wTb  ushort[256][128] bf16 (64 KB)
// [32768, 32768+B*L1)   : rank int (4 MB)
// next 1024             : cnt int
// then                  : y float B*K2*C (16 MB)
constexpr size_t WT_OFF   = 0;
constexpr size_t RANK_OFF = 32768;
constexpr size_t CNT_OFF  = RANK_OFF + (size_t)B_ * L1_;
constexpr size_t Y_OFF    = CNT_OFF + 1024;

__device__ inline ushort f2bf(float f) {
    uint u = __builtin_bit_cast(uint, f);
    u += 0x7fffu + ((u >> 16) & 1u);       // RNE (inputs finite)
    return (ushort)(u >> 16);
}

// ---------------- prep: w_lat[e][c][s] -> bf16 wTb[e][k], k = s*16+c --------
__global__ void prep_wT(const float* __restrict__ w_lat, ushort* __restrict__ wTb) {
    int e = threadIdx.x;     // 0..255, one block
#pragma unroll 8
    for (int kq = 0; kq < 32; ++kq) {     // 4 k per iter -> one uint2 store
        ushort u[4];
#pragma unroll
        for (int j = 0; j < 4; ++j) {
            int k = kq * 4 + j;
            int c = k & 15, s = k >> 4;
            u[j] = f2bf(w_lat[e * (C_ * KS_) + c * KS_ + s]);
        }
        uint2 pk;
        pk.x = ((uint)u[1] << 16) | u[0];
        pk.y = ((uint)u[3] << 16) | u[2];
        *(uint2*)(wTb + e * 128 + kq * 4) = pk;
    }
}

// ---------------- pass 1: per-segment mask counts (SEG = 1024 tokens) -------
__global__ void count_kernel(const int* __restrict__ value, int* __restrict__ cnt) {
    int b = blockIdx.x >> 6, seg = blockIdx.x & 63, tid = threadIdx.x;
    const int4 v = *(const int4*)(value + (size_t)b * S_ + seg * 1024 + tid * 4);
    int c = (v.x == 2) + (v.y == 2) + (v.z == 2) + (v.w == 2);
    __shared__ int sd[256];
    sd[tid] = c;
    __syncthreads();
    for (int o = 128; o > 0; o >>= 1) {
        if (tid < o) sd[tid] += sd[tid + o];
        __syncthreads();
    }
    if (tid == 0) cnt[blockIdx.x] = sd[0];
}

// ---------------- pass 2: exclusive scan of 64 segment counts per batch -----
__global__ void scan_kernel(int* __restrict__ cnt) {
    int tid = threadIdx.x;                 // 1024 threads: (b = tid>>6, seg = tid&63)
    int c = cnt[tid];
    __shared__ int sd[1024];
    sd[tid] = c;
    __syncthreads();
    for (int o = 1; o < 64; o <<= 1) {
        int t = ((tid & 63) >= o) ? sd[tid - o] : 0;
        __syncthreads();
        sd[tid] += t;
        __syncthreads();
    }
    cnt[tid] = sd[tid] - c;                // exclusive
}

// ---------------- pass 3: per-token rank = cumsum(mask)-1 -------------------
__global__ void rank_kernel(const int* __restrict__ value, const int* __restrict__ cnt,
                            int* __restrict__ rank) {
    int b = blockIdx.x >> 6, seg = blockIdx.x & 63, tid = threadIdx.x;
    size_t base = (size_t)b * S_ + seg * 1024 + tid * 4;
    const int4 v = *(const int4*)(value + base);
    int m0 = (v.x == 2), m1 = (v.y == 2), m2 = (v.z == 2), m3 = (v.w == 2);
    int c = m0 + m1 + m2 + m3;
    __shared__ int sd[256];
    sd[tid] = c;
    __syncthreads();
    for (int o = 1; o < 256; o <<= 1) {
        int t = (tid >= o) ? sd[tid - o] : 0;
        __syncthreads();
        sd[tid] += t;
        __syncthreads();
    }
    int run = cnt[blockIdx.x] + sd[tid] - c;   // exclusive prefix for this thread
    int4 r;
    run += m0; r.x = run - 1;
    run += m1; r.y = run - 1;
    run += m2; r.z = run - 1;
    run += m3; r.w = run - 1;
    *(int4*)(rank + (size_t)b * L1_ + seg * 1024 + tid * 4) = r;
}

// ---------------- y conv: one thread per (b,k) -------------------------------
__global__ void y_kernel(const int* __restrict__ value, const int* __restrict__ depth,
                         const int* __restrict__ pos,
                         const float* __restrict__ w_v2, const float* __restrict__ b_v2,
                         const float* __restrict__ w_d2, const float* __restrict__ b_d2,
                         const float* __restrict__ w_p2, const float* __restrict__ b_p2,
                         float* __restrict__ y) {
    int idx = blockIdx.x * 256 + threadIdx.x;       // = b*K2_ + k
    size_t g = (size_t)(idx >> 14) * S_ + L1_ + (size_t)(idx & (K2_ - 1)) * KS_;
    int4 va = *(const int4*)(value + g), vb = *(const int4*)(value + g + 4);
    int4 da = *(const int4*)(depth + g), db = *(const int4*)(depth + g + 4);
    float vv[8] = {(float)va.x, (float)va.y, (float)va.z, (float)va.w,
                   (float)vb.x, (float)vb.y, (float)vb.z, (float)vb.w};
    float dd[8] = {(float)da.x, (float)da.y, (float)da.z, (float)da.w,
                   (float)db.x, (float)db.y, (float)db.z, (float)db.w};
    size_t p = g * SD_;
    int pi[24];
#pragma unroll
    for (int q = 0; q < 6; ++q) {
        int4 t = *(const int4*)(pos + p + q * 4);
        pi[q * 4 + 0] = t.x; pi[q * 4 + 1] = t.y; pi[q * 4 + 2] = t.z; pi[q * 4 + 3] = t.w;
    }
    float pp[24];
#pragma unroll
    for (int q = 0; q < 24; ++q) pp[q] = (float)pi[q];

    float o[16];
#pragma unroll
    for (int c = 0; c < C_; ++c) {
        float acc = b_v2[c] + b_d2[c] + b_p2[c] + b_p2[C_ + c] + b_p2[2 * C_ + c];
#pragma unroll
        for (int s = 0; s < KS_; ++s) {
            acc = fmaf(vv[s], w_v2[c * KS_ + s], acc);
            acc = fmaf(dd[s], w_d2[c * KS_ + s], acc);
            acc = fmaf(pp[s * 3 + 0], w_p2[(0 * C_ + c) * KS_ + s], acc);
            acc = fmaf(pp[s * 3 + 1], w_p2[(1 * C_ + c) * KS_ + s], acc);
            acc = fmaf(pp[s * 3 + 2], w_p2[(2 * C_ + c) * KS_ + s], acc);
        }
        o[c] = acc;
    }
    float4* yo = (float4*)(y + (size_t)idx * C_);
    yo[0] = make_float4(o[0],  o[1],  o[2],  o[3]);
    yo[1] = make_float4(o[4],  o[5],  o[6],  o[7]);
    yo[2] = make_float4(o[8],  o[9],  o[10], o[11]);
    yo[3] = make_float4(o[12], o[13], o[14], o[15]);
}

// ---------------- fused x-build + latent GEMM via bf16 MFMA ------------------
// block = 512 threads (8 waves). M=256 out-rows x N=256 e, K=128 (single step).
// LDS: xs[256 rows][128 k] bf16 (64 KB, XOR-swizzled) + wsB[256 e][128 k] bf16
// (64 KB, XOR-swizzled). Wave grid 4M x 2N: each wave 64 rows x 128 cols.
// mfma_f32_16x16x32_bf16: A/B frag = 8 bf16, lane: row/col = lane&15,
// k = (lane>>4)*8 + j. C/D: col = lane&15, row = (lane>>4)*4 + reg.
__global__ __launch_bounds__(512) void out_kernel(
    const int* __restrict__ value, const int* __restrict__ depth,
    const int* __restrict__ pos,
    const float* __restrict__ w_v1, const float* __restrict__ b_v1,
    const float* __restrict__ w_d1, const float* __restrict__ b_d1,
    const float* __restrict__ w_p1, const float* __restrict__ b_p1,
    const float* __restrict__ b_lat,
    const ushort* __restrict__ wTb, const int* __restrict__ rank,
    const float* __restrict__ y, float* __restrict__ out) {
    extern __shared__ __align__(16) char smem[];   // 131072 B
    char* xs  = smem;            // [256][256 B]
    char* wsB = smem + 65536;    // [256][256 B]
    __shared__ float wA[96];     // [0:16) wv1 [16:32) wd1 [32:48) combined bias [48:96) wp1

    const int tid = threadIdx.x;
    const int b = blockIdx.x >> 5, tile = blockIdx.x & 31;

    // -------- stage W into LDS (swizzled): thread covers 128 B of wTb
    {
        const uint4* src = (const uint4*)((const char*)wTb + (size_t)tid * 128);
        uint4 v[8];
#pragma unroll
        for (int q = 0; q < 8; ++q) v[q] = src[q];
        int e = tid >> 1, half = tid & 1, swz = (e & 7) << 4;
#pragma unroll
        for (int q = 0; q < 8; ++q)
            *(uint4*)(wsB + e * 256 + ((half * 128 + q * 16) ^ swz)) = v[q];
    }
    if (tid < 16) {
        wA[tid]      = w_v1[tid];
        wA[16 + tid] = w_d1[tid];
        wA[32 + tid] = b_v1[tid] + b_d1[tid] + b_p1[tid] + b_p1[16 + tid] + b_p1[32 + tid];
    }
    if (tid < 48) wA[48 + tid] = w_p1[tid];
    __syncthreads();

    // -------- Phase A: build xs (bf16, swizzled). 2048 tokens, 4 per thread.
#pragma unroll
    for (int i = 0; i < 4; ++i) {
        int t_loc = i * 512 + tid;
        int row = t_loc >> 3, s = t_loc & 7;
        size_t l  = (size_t)tile * 2048 + t_loc;
        size_t gl = (size_t)b * S_ + l;
        int v = value[gl];
        float xv[16];
        if (v == 2) {
            int k = rank[(size_t)b * L1_ + l];
            const float4* yp = (const float4*)(y + ((size_t)b * K2_ + (size_t)k) * C_);
            float4 y0 = yp[0], y1 = yp[1], y2 = yp[2], y3 = yp[3];
            xv[0]  = y0.x; xv[1]  = y0.y; xv[2]  = y0.z; xv[3]  = y0.w;
            xv[4]  = y1.x; xv[5]  = y1.y; xv[6]  = y1.z; xv[7]  = y1.w;
            xv[8]  = y2.x; xv[9]  = y2.y; xv[10] = y2.z; xv[11] = y2.w;
            xv[12] = y3.x; xv[13] = y3.y; xv[14] = y3.z; xv[15] = y3.w;
        } else {
            float fv = (float)v, fd = (float)depth[gl];
            int4 p = *(const int4*)(pos + gl * 3);   // w lane unused
            float p0 = (float)p.x, p1 = (float)p.y, p2 = (float)p.z;
#pragma unroll
            for (int c = 0; c < 16; ++c) {
                float acc = wA[32 + c];
                acc = fmaf(fv, wA[c],      acc);
                acc = fmaf(fd, wA[16 + c], acc);
                acc = fmaf(p0, wA[48 + c], acc);
                acc = fmaf(p1, wA[64 + c], acc);
                acc = fmaf(p2, wA[80 + c], acc);
                xv[c] = acc;
            }
        }
        uint pk[8];
#pragma unroll
        for (int q = 0; q < 8; ++q)
            pk[q] = ((uint)f2bf(xv[2 * q + 1]) << 16) | f2bf(xv[2 * q]);
        uint4 lo = make_uint4(pk[0], pk[1], pk[2], pk[3]);
        uint4 hi = make_uint4(pk[4], pk[5], pk[6], pk[7]);
        int swz = (row & 7) << 4;
        *(uint4*)(xs + row * 256 + ((s * 32)      ^ swz)) = lo;
        *(uint4*)(xs + row * 256 + ((s * 32 + 16) ^ swz)) = hi;
    }
    __syncthreads();

    // -------- MFMA phase: wave (wm,wn) owns rows [wm*64, +64) x cols [wn*128, +128)
    const int lane = tid & 63, w = tid >> 6;
    const int wm = w >> 1, wn = w & 1;
    const int lrow = lane & 15, lk = lane >> 4;
    const int swz = (lrow & 7) << 4;

    f32x4 acc[4][8];
#pragma unroll
    for (int m = 0; m < 4; ++m)
#pragma unroll
        for (int n = 0; n < 8; ++n)
            acc[m][n] = (f32x4){0.f, 0.f, 0.f, 0.f};

#pragma unroll
    for (int k = 0; k < 4; ++k) {
        bf16x8 a[4];
#pragma unroll
        for (int m = 0; m < 4; ++m)
            a[m] = *(const bf16x8*)(xs + (wm * 64 + m * 16 + lrow) * 256
                                       + ((k * 64 + lk * 16) ^ swz));
#pragma unroll
        for (int n = 0; n < 8; ++n) {
            bf16x8 bb = *(const bf16x8*)(wsB + (wn * 128 + n * 16 + lrow) * 256
                                             + ((k * 64 + lk * 16) ^ swz));
#pragma unroll
            for (int m = 0; m < 4; ++m)
                acc[m][n] = __builtin_amdgcn_mfma_f32_16x16x32_bf16(a[m], bb, acc[m][n], 0, 0, 0);
        }
    }

    // -------- epilogue: direct f32 stores (64B-contiguous per lane quartet)
    size_t rowbase = (size_t)b * T_ + (size_t)tile * 256;
#pragma unroll
    for (int n = 0; n < 8; ++n) {
        int col = wn * 128 + n * 16 + lrow;
        float bl = b_lat[col];
#pragma unroll
        for (int m = 0; m < 4; ++m) {
            int r0 = wm * 64 + m * 16 + lk * 4;
            size_t o = (rowbase + r0) * E_ + col;
#pragma unroll
            for (int j = 0; j < 4; ++j)
                out[o + (size_t)j * E_] = acc[m][n][j] + bl;
        }
    }
}

// ---------------- launch ------------------------------------------------------
extern "C" void kernel_launch(void* const* d_in, const int* in_sizes, int n_in,
                              void* d_out, int out_size, void* d_ws, size_t ws_size,
                              hipStream_t stream) {
    const int*   value = (const int*)d_in[0];
    const int*   depth = (const int*)d_in[1];
    const int*   pos   = (const int*)d_in[2];
    // d_in[3] = len1 (static 65536, baked into constants)
    const float* w_v1 = (const float*)d_in[4];
    const float* b_v1 = (const float*)d_in[5];
    const float* w_d1 = (const float*)d_in[6];
    const float* b_d1 = (const float*)d_in[7];
    const float* w_p1 = (const float*)d_in[8];
    const float* b_p1 = (const float*)d_in[9];
    const float* w_v2 = (const float*)d_in[10];
    const float* b_v2 = (const float*)d_in[11];
    const float* w_d2 = (const float*)d_in[12];
    const float* b_d2 = (const float*)d_in[13];
    const float* w_p2 = (const float*)d_in[14];
    const float* b_p2 = (const float*)d_in[15];
    const float* w_lat = (const float*)d_in[16];
    const float* b_lat = (const float*)d_in[17];

    float* outp = (float*)d_out;
    float* wsf  = (float*)d_ws;
    int*   wsi  = (int*)d_ws;

    ushort* wTb = (ushort*)(wsf + WT_OFF);
    int*    rank = wsi + RANK_OFF;
    int*    cnt  = wsi + CNT_OFF;
    float*  y    = wsf + Y_OFF;

    prep_wT<<<1, 256, 0, stream>>>(w_lat, wTb);
    count_kernel<<<B_ * 64, 256, 0, stream>>>(value, cnt);
    scan_kernel<<<1, 1024, 0, stream>>>(cnt);
    rank_kernel<<<B_ * 64, 256, 0, stream>>>(value, cnt, rank);
    y_kernel<<<(B_ * K2_) / 256, 256, 0, stream>>>(value, depth, pos,
                                                   w_v2, b_v2, w_d2, b_d2, w_p2, b_p2, y);
    out_kernel<<<512, 512, 131072, stream>>>(value, depth, pos,
                                             w_v1, b_v1, w_d1, b_d1, w_p1, b_p1,
                                             b_lat, wTb, rank, y, outp);
}